// Round 5
// baseline (157.097 us; speedup 1.0000x reference)
//
#include <hip/hip_runtime.h>
#include <math.h>

#define BATCH 512   // scan lanes b' (== reference batch size)
#define FRAGS 256   // fragments per chain == blockDim.x

// Rigid transform: 12 floats, R row-major r[i*3+j], t = [9..11]. x' = R x + t.
// compose(A,B) = A o B (apply B first, then A).
__device__ __forceinline__ void compose(const float* A, const float* B, float* D) {
    float d[12];
    #pragma unroll
    for (int i = 0; i < 3; ++i) {
        #pragma unroll
        for (int j = 0; j < 3; ++j)
            d[i*3+j] = A[i*3+0]*B[0*3+j] + A[i*3+1]*B[1*3+j] + A[i*3+2]*B[2*3+j];
        d[9+i] = A[i*3+0]*B[9] + A[i*3+1]*B[10] + A[i*3+2]*B[11] + A[9+i];
    }
    #pragma unroll
    for (int k = 0; k < 12; ++k) D[k] = d[k];
}

// Frame of carry triple (a,b,c): R columns = [bc, n x bc, n], t = c.
__device__ __forceinline__ void frame_of(
    float ax, float ay, float az,
    float bx, float by, float bz,
    float cx, float cy, float cz,
    float* out /*12*/)
{
    float bcx = cx - bx, bcy = cy - by, bcz = cz - bz;
    float inv = rsqrtf(bcx*bcx + bcy*bcy + bcz*bcz + 1e-12f);
    bcx *= inv; bcy *= inv; bcz *= inv;
    float bax = bx - ax, bay = by - ay, baz = bz - az;
    float nx = bay*bcz - baz*bcy;
    float ny = baz*bcx - bax*bcz;
    float nz = bax*bcy - bay*bcx;
    inv = rsqrtf(nx*nx + ny*ny + nz*nz + 1e-12f);
    nx *= inv; ny *= inv; nz *= inv;
    float mx = ny*bcz - nz*bcy;
    float my = nz*bcx - nx*bcz;
    float mz = nx*bcy - ny*bcx;
    out[0] = bcx; out[1] = mx; out[2] = nx;
    out[3] = bcy; out[4] = my; out[5] = ny;
    out[6] = bcz; out[7] = mz; out[8] = nz;
    out[9] = cx; out[10] = cy; out[11] = cz;
}

__device__ __forceinline__ void nerf_step(
    float ax, float ay, float az,
    float bx, float by, float bz,
    float cx, float cy, float cz,
    float px, float py, float pz,
    float& ox, float& oy, float& oz)
{
    float bcx = cx - bx, bcy = cy - by, bcz = cz - bz;
    float inv = rsqrtf(bcx*bcx + bcy*bcy + bcz*bcz + 1e-12f);
    bcx *= inv; bcy *= inv; bcz *= inv;
    float bax = bx - ax, bay = by - ay, baz = bz - az;
    float nx = bay*bcz - baz*bcy;
    float ny = baz*bcx - bax*bcz;
    float nz = bax*bcy - bay*bcx;
    inv = rsqrtf(nx*nx + ny*ny + nz*nz + 1e-12f);
    nx *= inv; ny *= inv; nz *= inv;
    float mx = ny*bcz - nz*bcy;
    float my = nz*bcx - nx*bcz;
    float mz = nx*bcy - ny*bcx;
    ox = bcx*px + mx*py + nx*pz + cx;
    oy = bcy*px + my*py + ny*pz + cy;
    oz = bcz*px + mz*py + nz*pz + cz;
}

// One block per scan lane b' (the reference's post-reshape lane, NOT the
// logical batch index: reshape (L,B,3,3)->(3L,B,3) scrambles (b,d) so that
// step n=3l+k, lane b' consumes dih flat[l*1536 + 512k + b'] with bond-const
// index d_k = (2k + b') % 3). Thread f owns fragment f (rpf residues).
// Stage 1: local chain from canonical init -> frame H_f.
// Stage 2: LDS inclusive SE(3) scan (Hillis-Steele).
// Stage 3: G_f = S_{f-1}; recompute local chain, write G_f(x).
__global__ void __launch_bounds__(FRAGS) coord_fused(
    const float* __restrict__ dih, float* __restrict__ out, int L)
{
    const int b = blockIdx.x;           // scan lane b'
    const int f = threadIdx.x;
    const int rpf = L / FRAGS;          // 8 residues per fragment

    __shared__ float S[FRAGS][13];      // +1 pad: stride 13 -> conflict-free

    // Bond geometry, permuted per-lane: k-th step of each residue uses d_k.
    const float PI = 3.14159265358979323846f;
    float rc[3], rs[3];
    rc[0] = 145.801f * cosf(PI - 2.124f); rs[0] = 145.801f * sinf(PI - 2.124f);
    rc[1] = 152.326f * cosf(PI - 1.941f); rs[1] = 152.326f * sinf(PI - 1.941f);
    rc[2] = 132.868f * cosf(PI - 2.028f); rs[2] = 132.868f * sinf(PI - 2.028f);
    const int d0 = b % 3, d1 = (b + 2) % 3, d2 = (b + 1) % 3;
    const float rcl[3] = {rc[d0], rc[d1], rc[d2]};
    const float rsl[3] = {rs[d0], rs[d1], rs[d2]};

    // ---- Stage 1: local chain, frame H_f ----
    float ax = -0.70710678118654752f, ay = 1.22474487139158905f, az = 0.0f;
    float bx = -1.41421356237309505f, by = 0.0f, bz = 0.0f;
    float cx = 0.0f, cy = 0.0f, cz = 0.0f;

    for (int r = 0; r < rpf; ++r) {
        int l = f * rpf + r;
        const float* src = dih + (size_t)l * (3 * BATCH) + b;
        float dd[3];
        dd[0] = src[0];
        dd[1] = src[BATCH];
        dd[2] = src[2 * BATCH];
        #pragma unroll
        for (int k = 0; k < 3; ++k) {
            float sn, cs;
            __sincosf(dd[k], &sn, &cs);
            float ox, oy, oz;
            nerf_step(ax, ay, az, bx, by, bz, cx, cy, cz,
                      rcl[k], cs * rsl[k], sn * rsl[k], ox, oy, oz);
            ax = bx; ay = by; az = bz;
            bx = cx; by = cy; bz = cz;
            cx = ox; cy = oy; cz = oz;
        }
    }

    {
        float h[12];
        frame_of(ax, ay, az, bx, by, bz, cx, cy, cz, h);
        #pragma unroll
        for (int k = 0; k < 12; ++k) S[f][k] = h[k];
    }
    __syncthreads();

    // ---- Stage 2: inclusive scan over fragments (non-commutative) ----
    float tmp[12];
    for (int o = 1; o < FRAGS; o <<= 1) {
        const bool act = (f >= o);
        if (act) compose(&S[f - o][0], &S[f][0], tmp);
        __syncthreads();
        if (act) {
            #pragma unroll
            for (int k = 0; k < 12; ++k) S[f][k] = tmp[k];
        }
        __syncthreads();
    }

    float G[12];
    if (f == 0) {
        G[0]=1.f; G[1]=0.f; G[2]=0.f;
        G[3]=0.f; G[4]=1.f; G[5]=0.f;
        G[6]=0.f; G[7]=0.f; G[8]=1.f;
        G[9]=0.f; G[10]=0.f; G[11]=0.f;
    } else {
        #pragma unroll
        for (int k = 0; k < 12; ++k) G[k] = S[f - 1][k];
    }

    // ---- Stage 3: recompute local chain, transform, store ----
    ax = -0.70710678118654752f; ay = 1.22474487139158905f; az = 0.0f;
    bx = -1.41421356237309505f; by = 0.0f; bz = 0.0f;
    cx = 0.0f; cy = 0.0f; cz = 0.0f;

    for (int r = 0; r < rpf; ++r) {
        int l = f * rpf + r;
        const float* src = dih + (size_t)l * (3 * BATCH) + b;
        float dd[3];
        dd[0] = src[0];
        dd[1] = src[BATCH];
        dd[2] = src[2 * BATCH];
        #pragma unroll
        for (int k = 0; k < 3; ++k) {
            float sn, cs;
            __sincosf(dd[k], &sn, &cs);
            float ox, oy, oz;
            nerf_step(ax, ay, az, bx, by, bz, cx, cy, cz,
                      rcl[k], cs * rsl[k], sn * rsl[k], ox, oy, oz);
            ax = bx; ay = by; az = bz;
            bx = cx; by = cy; bz = cz;
            cx = ox; cy = oy; cz = oz;

            float gx = G[0]*ox + G[1]*oy + G[2]*oz + G[9];
            float gy = G[3]*ox + G[4]*oy + G[5]*oz + G[10];
            float gz = G[6]*ox + G[7]*oy + G[8]*oz + G[11];

            size_t n = (size_t)l * 3 + k;   // scan step index
            float* dst = out + (n * BATCH + b) * 3;
            dst[0] = gx; dst[1] = gy; dst[2] = gz;
        }
    }
}

extern "C" void kernel_launch(void* const* d_in, const int* in_sizes, int n_in,
                              void* d_out, int out_size, void* d_ws, size_t ws_size,
                              hipStream_t stream) {
    const float* dih = (const float*)d_in[0];
    float* out = (float*)d_out;

    int total = in_sizes[0];              // num_steps * batch * 3
    int L = total / (3 * BATCH);          // 2048 residues

    coord_fused<<<dim3(BATCH), dim3(FRAGS), 0, stream>>>(dih, out, L);
    (void)d_ws; (void)ws_size; (void)n_in; (void)out_size;
}

// Round 6
// 108.234 us; speedup vs baseline: 1.4514x; 1.4514x over previous
//
#include <hip/hip_runtime.h>
#include <math.h>

#define BATCH 512    // post-reshape scan lanes
#define FRAGS 256    // fragments per chain
#define GROUP 16     // fragments per scan group
#define NGRP  (FRAGS/GROUP)

// Rigid transform: 12 floats, R row-major r[i*3+j], t=[9..11]. x' = Rx + t.
// compose(A,B): A is the EARLIER prefix, B the later. (Verified in R5 pass.)
__device__ __forceinline__ void compose(const float* A, const float* B, float* D) {
    float d[12];
    #pragma unroll
    for (int i = 0; i < 3; ++i) {
        #pragma unroll
        for (int j = 0; j < 3; ++j)
            d[i*3+j] = A[i*3+0]*B[0*3+j] + A[i*3+1]*B[1*3+j] + A[i*3+2]*B[2*3+j];
        d[9+i] = A[i*3+0]*B[9] + A[i*3+1]*B[10] + A[i*3+2]*B[11] + A[9+i];
    }
    #pragma unroll
    for (int k = 0; k < 12; ++k) D[k] = d[k];
}

__device__ __forceinline__ void frame_of(
    float ax, float ay, float az,
    float bx, float by, float bz,
    float cx, float cy, float cz,
    float* out /*12*/)
{
    float bcx = cx - bx, bcy = cy - by, bcz = cz - bz;
    float inv = rsqrtf(bcx*bcx + bcy*bcy + bcz*bcz + 1e-12f);
    bcx *= inv; bcy *= inv; bcz *= inv;
    float bax = bx - ax, bay = by - ay, baz = bz - az;
    float nx = bay*bcz - baz*bcy;
    float ny = baz*bcx - bax*bcz;
    float nz = bax*bcy - bay*bcx;
    inv = rsqrtf(nx*nx + ny*ny + nz*nz + 1e-12f);
    nx *= inv; ny *= inv; nz *= inv;
    float mx = ny*bcz - nz*bcy;
    float my = nz*bcx - nx*bcz;
    float mz = nx*bcy - ny*bcx;
    out[0] = bcx; out[1] = mx; out[2] = nx;
    out[3] = bcy; out[4] = my; out[5] = ny;
    out[6] = bcz; out[7] = mz; out[8] = nz;
    out[9] = cx; out[10] = cy; out[11] = cz;
}

__device__ __forceinline__ void nerf_step(
    float ax, float ay, float az,
    float bx, float by, float bz,
    float cx, float cy, float cz,
    float px, float py, float pz,
    float& ox, float& oy, float& oz)
{
    float bcx = cx - bx, bcy = cy - by, bcz = cz - bz;
    float inv = rsqrtf(bcx*bcx + bcy*bcy + bcz*bcz + 1e-12f);
    bcx *= inv; bcy *= inv; bcz *= inv;
    float bax = bx - ax, bay = by - ay, baz = bz - az;
    float nx = bay*bcz - baz*bcy;
    float ny = baz*bcx - bax*bcz;
    float nz = bax*bcy - bay*bcx;
    inv = rsqrtf(nx*nx + ny*ny + nz*nz + 1e-12f);
    nx *= inv; ny *= inv; nz *= inv;
    float mx = ny*bcz - nz*bcy;
    float my = nz*bcx - nx*bcz;
    float mz = nx*bcy - ny*bcx;
    ox = bcx*px + mx*py + nx*pz + cx;
    oy = bcy*px + my*py + ny*pz + cy;
    oz = bcz*px + mz*py + nz*pz + cz;
}

// Per-lane permuted bond constants. Reshape (L,B,3,3)->(3L,B,3) makes scan
// lane b at residue l, step k consume dih flat[l*1536 + 512k + b], whose
// bond-const index is (512k+b)%3; with 512%3==2 this is the pattern
// d = {b%3, (b+2)%3, (b+1)%3}. (Verified: R5 passed.)
__device__ __forceinline__ void lane_consts(int b, float* rcl, float* rsl) {
    const float PI = 3.14159265358979323846f;
    float rc[3], rs[3];
    rc[0] = 145.801f * cosf(PI - 2.124f); rs[0] = 145.801f * sinf(PI - 2.124f);
    rc[1] = 152.326f * cosf(PI - 1.941f); rs[1] = 152.326f * sinf(PI - 1.941f);
    rc[2] = 132.868f * cosf(PI - 2.028f); rs[2] = 132.868f * sinf(PI - 2.028f);
    const int d0 = b % 3, d1 = (b + 2) % 3, d2 = (b + 1) % 3;
    rcl[0] = rc[d0]; rcl[1] = rc[d1]; rcl[2] = rc[d2];
    rsl[0] = rs[d0]; rsl[1] = rs[d1]; rsl[2] = rs[d2];
}

// Run the rpf-residue local chain for (f, b) from the canonical init.
// Leaves final carry triple in (a,b,c). If out != nullptr, also transforms
// each point by G and stores.
__device__ __forceinline__ void local_chain(
    const float* __restrict__ dih, int f, int b, int rpf,
    const float* rcl, const float* rsl,
    float& ax, float& ay, float& az,
    float& bx, float& by, float& bz,
    float& cx, float& cy, float& cz,
    const float* G, float* __restrict__ out)
{
    ax = -0.70710678118654752f; ay = 1.22474487139158905f; az = 0.0f;
    bx = -1.41421356237309505f; by = 0.0f; bz = 0.0f;
    cx = 0.0f; cy = 0.0f; cz = 0.0f;

    for (int r = 0; r < rpf; ++r) {
        int l = f * rpf + r;
        const float* src = dih + (size_t)l * (3 * BATCH) + b;
        float dd[3];
        dd[0] = src[0];
        dd[1] = src[BATCH];
        dd[2] = src[2 * BATCH];
        #pragma unroll
        for (int k = 0; k < 3; ++k) {
            float sn, cs;
            __sincosf(dd[k], &sn, &cs);
            float ox, oy, oz;
            nerf_step(ax, ay, az, bx, by, bz, cx, cy, cz,
                      rcl[k], cs * rsl[k], sn * rsl[k], ox, oy, oz);
            ax = bx; ay = by; az = bz;
            bx = cx; by = cy; bz = cz;
            cx = ox; cy = oy; cz = oz;
            if (out) {
                float gx = G[0]*ox + G[1]*oy + G[2]*oz + G[9];
                float gy = G[3]*ox + G[4]*oy + G[5]*oz + G[10];
                float gz = G[6]*ox + G[7]*oy + G[8]*oz + G[11];
                size_t n = (size_t)l * 3 + k;
                float* dst = out + (n * BATCH + b) * 3;
                dst[0] = gx; dst[1] = gy; dst[2] = gz;
            }
        }
    }
}

// Phase A: thread (f,b), b-fast. Coalesced input reads; frame to H[f][k][b].
__global__ void __launch_bounds__(256) frames_k(
    const float* __restrict__ dih, float* __restrict__ H, int rpf)
{
    int t = blockIdx.x * blockDim.x + threadIdx.x;
    int b = t & (BATCH - 1);
    int f = t >> 9;
    if (f >= FRAGS) return;

    float rcl[3], rsl[3];
    lane_consts(b, rcl, rsl);

    float ax, ay, az, bx, by, bz, cx, cy, cz;
    local_chain(dih, f, b, rpf, rcl, rsl, ax, ay, az, bx, by, bz, cx, cy, cz,
                nullptr, nullptr);

    float h[12];
    frame_of(ax, ay, az, bx, by, bz, cx, cy, cz, h);
    #pragma unroll
    for (int k = 0; k < 12; ++k)
        H[((size_t)f * 12 + k) * BATCH + b] = h[k];
}

// Phase B1: thread (g,b), b-fast. In-place group-local inclusive prefixes.
__global__ void __launch_bounds__(256) scan_groups_k(float* __restrict__ H)
{
    int t = blockIdx.x * blockDim.x + threadIdx.x;
    int b = t & (BATCH - 1);
    int g = t >> 9;
    if (g >= NGRP) return;
    int f0 = g * GROUP;

    float acc[12];
    #pragma unroll
    for (int k = 0; k < 12; ++k)
        acc[k] = H[((size_t)f0 * 12 + k) * BATCH + b];
    for (int j = 1; j < GROUP; ++j) {
        float h[12];
        #pragma unroll
        for (int k = 0; k < 12; ++k)
            h[k] = H[((size_t)(f0 + j) * 12 + k) * BATCH + b];
        compose(acc, h, acc);
        #pragma unroll
        for (int k = 0; k < 12; ++k)
            H[((size_t)(f0 + j) * 12 + k) * BATCH + b] = acc[k];
    }
}

// Phase B2: thread b. Exclusive scan of group totals -> E[g][k][b].
__global__ void __launch_bounds__(256) scan_tops_k(
    const float* __restrict__ H, float* __restrict__ E)
{
    int b = blockIdx.x * blockDim.x + threadIdx.x;
    if (b >= BATCH) return;

    float acc[12] = {1,0,0, 0,1,0, 0,0,1, 0,0,0};
    for (int g = 0; g < NGRP; ++g) {
        #pragma unroll
        for (int k = 0; k < 12; ++k)
            E[((size_t)g * 12 + k) * BATCH + b] = acc[k];
        float tot[12];
        int flast = g * GROUP + GROUP - 1;
        #pragma unroll
        for (int k = 0; k < 12; ++k)
            tot[k] = H[((size_t)flast * 12 + k) * BATCH + b];
        compose(acc, tot, acc);
    }
}

// Phase C: thread (f,b), b-fast. G_f = E_g o P_{f-1}; recompute chain,
// transform, coalesced 12B/lane stores.
__global__ void __launch_bounds__(256) apply_k(
    const float* __restrict__ dih, const float* __restrict__ H,
    const float* __restrict__ E, float* __restrict__ out, int rpf)
{
    int t = blockIdx.x * blockDim.x + threadIdx.x;
    int b = t & (BATCH - 1);
    int f = t >> 9;
    if (f >= FRAGS) return;
    int g = f / GROUP, j = f % GROUP;

    float G[12];
    #pragma unroll
    for (int k = 0; k < 12; ++k)
        G[k] = E[((size_t)g * 12 + k) * BATCH + b];
    if (j > 0) {
        float p[12];
        #pragma unroll
        for (int k = 0; k < 12; ++k)
            p[k] = H[((size_t)(f - 1) * 12 + k) * BATCH + b];
        compose(G, p, G);
    }

    float rcl[3], rsl[3];
    lane_consts(b, rcl, rsl);

    float ax, ay, az, bx, by, bz, cx, cy, cz;
    local_chain(dih, f, b, rpf, rcl, rsl, ax, ay, az, bx, by, bz, cx, cy, cz,
                G, out);
}

extern "C" void kernel_launch(void* const* d_in, const int* in_sizes, int n_in,
                              void* d_out, int out_size, void* d_ws, size_t ws_size,
                              hipStream_t stream) {
    const float* dih = (const float*)d_in[0];
    float* out = (float*)d_out;

    int total = in_sizes[0];              // num_steps * batch * 3
    int L = total / (3 * BATCH);          // 2048 residues
    int rpf = L / FRAGS;                  // 8

    float* H = (float*)d_ws;                       // FRAGS*12*BATCH floats (6.3 MB)
    float* E = H + (size_t)FRAGS * 12 * BATCH;     // NGRP*12*BATCH floats (0.4 MB)

    dim3 blk(256);
    frames_k<<<dim3(FRAGS * BATCH / 256), blk, 0, stream>>>(dih, H, rpf);
    scan_groups_k<<<dim3(NGRP * BATCH / 256), blk, 0, stream>>>(H);
    scan_tops_k<<<dim3(BATCH / 256), blk, 0, stream>>>(H, E);
    apply_k<<<dim3(FRAGS * BATCH / 256), blk, 0, stream>>>(dih, H, E, out, rpf);
    (void)ws_size; (void)n_in; (void)out_size;
}

// Round 7
// 94.549 us; speedup vs baseline: 1.6615x; 1.1447x over previous
//
#include <hip/hip_runtime.h>
#include <math.h>

#define BATCH 512    // post-reshape scan lanes
#define FRAGS 256    // fragments per chain (rpf = L/FRAGS = 8 residues each)
#define GROUP 16     // fragments per scan group == frags per K1 block
#define NGRP  (FRAGS/GROUP)   // 16
#define BTILE 16     // batch lanes per K1 block

// Rigid transform: 12 floats, R row-major r[i*3+j], t=[9..11]. x' = Rx + t.
// compose(A,B): A is the EARLIER prefix, B the later. (Verified: R5/R6 pass.)
__device__ __forceinline__ void compose(const float* A, const float* B, float* D) {
    float d[12];
    #pragma unroll
    for (int i = 0; i < 3; ++i) {
        #pragma unroll
        for (int j = 0; j < 3; ++j)
            d[i*3+j] = A[i*3+0]*B[0*3+j] + A[i*3+1]*B[1*3+j] + A[i*3+2]*B[2*3+j];
        d[9+i] = A[i*3+0]*B[9] + A[i*3+1]*B[10] + A[i*3+2]*B[11] + A[9+i];
    }
    #pragma unroll
    for (int k = 0; k < 12; ++k) D[k] = d[k];
}

__device__ __forceinline__ void frame_of(
    float ax, float ay, float az,
    float bx, float by, float bz,
    float cx, float cy, float cz,
    float* out /*12*/)
{
    float bcx = cx - bx, bcy = cy - by, bcz = cz - bz;
    float inv = rsqrtf(bcx*bcx + bcy*bcy + bcz*bcz + 1e-12f);
    bcx *= inv; bcy *= inv; bcz *= inv;
    float bax = bx - ax, bay = by - ay, baz = bz - az;
    float nx = bay*bcz - baz*bcy;
    float ny = baz*bcx - bax*bcz;
    float nz = bax*bcy - bay*bcx;
    inv = rsqrtf(nx*nx + ny*ny + nz*nz + 1e-12f);
    nx *= inv; ny *= inv; nz *= inv;
    float mx = ny*bcz - nz*bcy;
    float my = nz*bcx - nx*bcz;
    float mz = nx*bcy - ny*bcx;
    out[0] = bcx; out[1] = mx; out[2] = nx;
    out[3] = bcy; out[4] = my; out[5] = ny;
    out[6] = bcz; out[7] = mz; out[8] = nz;
    out[9] = cx; out[10] = cy; out[11] = cz;
}

__device__ __forceinline__ void nerf_step(
    float ax, float ay, float az,
    float bx, float by, float bz,
    float cx, float cy, float cz,
    float px, float py, float pz,
    float& ox, float& oy, float& oz)
{
    float bcx = cx - bx, bcy = cy - by, bcz = cz - bz;
    float inv = rsqrtf(bcx*bcx + bcy*bcy + bcz*bcz + 1e-12f);
    bcx *= inv; bcy *= inv; bcz *= inv;
    float bax = bx - ax, bay = by - ay, baz = bz - az;
    float nx = bay*bcz - baz*bcy;
    float ny = baz*bcx - bax*bcz;
    float nz = bax*bcy - bay*bcx;
    inv = rsqrtf(nx*nx + ny*ny + nz*nz + 1e-12f);
    nx *= inv; ny *= inv; nz *= inv;
    float mx = ny*bcz - nz*bcy;
    float my = nz*bcx - nx*bcz;
    float mz = nx*bcy - ny*bcx;
    ox = bcx*px + mx*py + nx*pz + cx;
    oy = bcy*px + my*py + ny*pz + cy;
    oz = bcz*px + mz*py + nz*pz + cz;
}

// Per-lane permuted bond constants. Reshape (L,B,3,3)->(3L,B,3) makes scan
// lane b at residue l, step k consume dih flat[l*1536 + 512k + b]; bond-const
// index = (512k+b)%3 -> pattern d = {b%3, (b+2)%3, (b+1)%3}. (Verified R5.)
__device__ __forceinline__ void lane_consts(int b, float* rcl, float* rsl) {
    const float PI = 3.14159265358979323846f;
    float rc[3], rs[3];
    rc[0] = 145.801f * cosf(PI - 2.124f); rs[0] = 145.801f * sinf(PI - 2.124f);
    rc[1] = 152.326f * cosf(PI - 1.941f); rs[1] = 152.326f * sinf(PI - 1.941f);
    rc[2] = 132.868f * cosf(PI - 2.028f); rs[2] = 132.868f * sinf(PI - 2.028f);
    const int d0 = b % 3, d1 = (b + 2) % 3, d2 = (b + 1) % 3;
    rcl[0] = rc[d0]; rcl[1] = rc[d1]; rcl[2] = rc[d2];
    rsl[0] = rs[d0]; rsl[1] = rs[d1]; rsl[2] = rs[d2];
}

// Local chain for (f,b) from the canonical init; leaves carry in (a,b,c).
// If out != nullptr, also transforms each point by G and stores (coalesced:
// wave covers 64 consecutive b -> 768 B contiguous per (l,k)).
__device__ __forceinline__ void local_chain(
    const float* __restrict__ dih, int f, int b, int rpf,
    const float* rcl, const float* rsl,
    float& ax, float& ay, float& az,
    float& bx, float& by, float& bz,
    float& cx, float& cy, float& cz,
    const float* G, float* __restrict__ out)
{
    ax = -0.70710678118654752f; ay = 1.22474487139158905f; az = 0.0f;
    bx = -1.41421356237309505f; by = 0.0f; bz = 0.0f;
    cx = 0.0f; cy = 0.0f; cz = 0.0f;

    for (int r = 0; r < rpf; ++r) {
        int l = f * rpf + r;
        const float* src = dih + (size_t)l * (3 * BATCH) + b;
        float dd[3];
        dd[0] = src[0];
        dd[1] = src[BATCH];
        dd[2] = src[2 * BATCH];
        #pragma unroll
        for (int k = 0; k < 3; ++k) {
            float sn, cs;
            __sincosf(dd[k], &sn, &cs);
            float ox, oy, oz;
            nerf_step(ax, ay, az, bx, by, bz, cx, cy, cz,
                      rcl[k], cs * rsl[k], sn * rsl[k], ox, oy, oz);
            ax = bx; ay = by; az = bz;
            bx = cx; by = cy; bz = cz;
            cx = ox; cy = oy; cz = oz;
            if (out) {
                float gx = G[0]*ox + G[1]*oy + G[2]*oz + G[9];
                float gy = G[3]*ox + G[4]*oy + G[5]*oz + G[10];
                float gz = G[6]*ox + G[7]*oy + G[8]*oz + G[11];
                size_t n = (size_t)l * 3 + k;
                float* dst = out + (n * BATCH + b) * 3;
                dst[0] = gx; dst[1] = gy; dst[2] = gz;
            }
        }
    }
}

// K1 (= phase A + B1): block = BTILE b-lanes x GROUP frags (one scan group).
// Each thread: local chain -> frame H into LDS; 4-step Hillis-Steele scan
// over the group's 16 frags; write inclusive prefixes P[f][k][b].
__global__ void __launch_bounds__(BTILE * GROUP) frames_scan_k(
    const float* __restrict__ dih, float* __restrict__ P, int rpf)
{
    const int btile = blockIdx.x & (BATCH / BTILE - 1);   // 32 tiles
    const int g     = blockIdx.x >> 5;                    // 16 groups
    const int bsub  = threadIdx.x & (BTILE - 1);
    const int j     = threadIdx.x >> 4;                   // frag within group
    const int f     = g * GROUP + j;
    const int b     = btile * BTILE + bsub;

    __shared__ float S[GROUP * BTILE * 13];               // stride 13: conflict-free
    float* Srow = &S[(size_t)threadIdx.x * 13];

    float rcl[3], rsl[3];
    lane_consts(b, rcl, rsl);

    float ax, ay, az, bx, by, bz, cx, cy, cz;
    local_chain(dih, f, b, rpf, rcl, rsl, ax, ay, az, bx, by, bz, cx, cy, cz,
                nullptr, nullptr);

    {
        float h[12];
        frame_of(ax, ay, az, bx, by, bz, cx, cy, cz, h);
        #pragma unroll
        for (int k = 0; k < 12; ++k) Srow[k] = h[k];
    }
    __syncthreads();

    // Hillis-Steele inclusive scan over j (non-commutative, left-compose).
    float tmp[12];
    #pragma unroll
    for (int o = 1; o < GROUP; o <<= 1) {
        const bool act = (j >= o);
        if (act) compose(&S[(size_t)(threadIdx.x - o * BTILE) * 13], Srow, tmp);
        __syncthreads();
        if (act) {
            #pragma unroll
            for (int k = 0; k < 12; ++k) Srow[k] = tmp[k];
        }
        __syncthreads();
    }

    #pragma unroll
    for (int k = 0; k < 12; ++k)
        P[((size_t)f * 12 + k) * BATCH + b] = Srow[k];
}

// K2 (= phase B2 + C): thread (f,b), b-fast. f is block-uniform (256-thread
// blocks, b spans 512 over 2 blocks per f). E_g composed inline from group
// totals T_g' = P[16g'+15] (L2-hot, <=15 composes); G_f = E_g o P_{f-1};
// recompute chain, transform, coalesced stores.
__global__ void __launch_bounds__(256) apply_k(
    const float* __restrict__ dih, const float* __restrict__ P,
    float* __restrict__ out, int rpf)
{
    int t = blockIdx.x * blockDim.x + threadIdx.x;
    int b = t & (BATCH - 1);
    int f = t >> 9;
    if (f >= FRAGS) return;
    int g = f >> 4, j = f & (GROUP - 1);

    float G[12];
    if (g == 0) {
        G[0]=1.f; G[1]=0.f; G[2]=0.f;
        G[3]=0.f; G[4]=1.f; G[5]=0.f;
        G[6]=0.f; G[7]=0.f; G[8]=1.f;
        G[9]=0.f; G[10]=0.f; G[11]=0.f;
    } else {
        #pragma unroll
        for (int k = 0; k < 12; ++k)
            G[k] = P[((size_t)(GROUP - 1) * 12 + k) * BATCH + b];  // T_0
        for (int gp = 1; gp < g; ++gp) {
            float tg[12];
            int fl = gp * GROUP + GROUP - 1;
            #pragma unroll
            for (int k = 0; k < 12; ++k)
                tg[k] = P[((size_t)fl * 12 + k) * BATCH + b];
            compose(G, tg, G);
        }
    }
    if (j > 0) {
        float p[12];
        #pragma unroll
        for (int k = 0; k < 12; ++k)
            p[k] = P[((size_t)(f - 1) * 12 + k) * BATCH + b];
        compose(G, p, G);
    }

    float rcl[3], rsl[3];
    lane_consts(b, rcl, rsl);

    float ax, ay, az, bx, by, bz, cx, cy, cz;
    local_chain(dih, f, b, rpf, rcl, rsl, ax, ay, az, bx, by, bz, cx, cy, cz,
                G, out);
}

extern "C" void kernel_launch(void* const* d_in, const int* in_sizes, int n_in,
                              void* d_out, int out_size, void* d_ws, size_t ws_size,
                              hipStream_t stream) {
    const float* dih = (const float*)d_in[0];
    float* out = (float*)d_out;

    int total = in_sizes[0];              // num_steps * batch * 3
    int L = total / (3 * BATCH);          // 2048 residues
    int rpf = L / FRAGS;                  // 8

    float* P = (float*)d_ws;              // FRAGS*12*BATCH floats (6.3 MB)

    frames_scan_k<<<dim3(NGRP * (BATCH / BTILE)), dim3(BTILE * GROUP), 0, stream>>>(
        dih, P, rpf);
    apply_k<<<dim3(FRAGS * BATCH / 256), dim3(256), 0, stream>>>(
        dih, P, out, rpf);
    (void)ws_size; (void)n_in; (void)out_size;
}